// Round 19
// baseline (321.657 us; speedup 1.0000x reference)
//
#include <hip/hip_runtime.h>
#include <hip/hip_bf16.h>
#include <math.h>

#define NB 2
#define CC 192
#define HH 256
#define WW 256
#define NHD 6
#define DH 32
#define C3 576   // 3*CC

typedef __attribute__((ext_vector_type(8))) short bf16x8;
typedef __attribute__((ext_vector_type(4))) float f32x4;

__device__ __forceinline__ ushort f2b(float v) {
    __hip_bfloat16 b = __float2bfloat16(v);
    return *reinterpret_cast<ushort*>(&b);
}
__device__ __forceinline__ float b2f(ushort u) {
    __hip_bfloat16 b;
    *reinterpret_cast<ushort*>(&b) = u;
    return __bfloat162float(b);
}
__device__ __forceinline__ float bu(ushort u) {
    uint x = (uint)u << 16;
    return __uint_as_float(x);
}
__device__ __forceinline__ float exp2_fast(float x) {
#if __has_builtin(__builtin_amdgcn_exp2f)
    return __builtin_amdgcn_exp2f(x);
#else
    return exp2f(x);
#endif
}
__device__ __forceinline__ uint pk2(float x, float y) {
    return (__float_as_uint(y) & 0xFFFF0000u) | (__float_as_uint(x) >> 16);
}
__device__ __forceinline__ void gl_lds16(const void* g, void* l) {
    __builtin_amdgcn_global_load_lds((const __attribute__((address_space(1))) void*)g,
                                     (__attribute__((address_space(3))) void*)l, 16, 0, 0);
}

// ---------------------------------------------------------------------------
// interleave pick: chunked so each type's local index == pbid (mod 8).
// Region [0,TTH): periods of CA A-blocks then CB B-blocks.  [TTH,...): tail
// is all-A (tailA=1, idx=pbid-nB) or all-B (idx=pbid-NA).
// (parameter renamed nB: "NB" is a macro!)
// ---------------------------------------------------------------------------
__device__ __forceinline__ void pick(int pbid, int CA, int CB, int NA, int nB,
                                     int TTH, int tailA, int& isA, int& idx) {
    if (pbid >= TTH) {
        isA = tailA;
        idx = tailA ? (pbid - nB) : (pbid - NA);
        return;
    }
    const int per = CA + CB, q = pbid / per, rm = pbid % per;
    if (rm < CA) { isA = 1; idx = q * CA + rm; }
    else         { isA = 0; idx = q * CB + (rm - CA); }
}

// ---------------------------------------------------------------------------
// prep_w: split w1 and wf fp32 -> bf16 hi/lo planes.
// ---------------------------------------------------------------------------
__global__ __launch_bounds__(256) void prep_w(const float* __restrict__ w1,
                                              const float* __restrict__ wf,
                                              ushort* __restrict__ Whi,
                                              ushort* __restrict__ Wlo) {
    int i = blockIdx.x * 256 + threadIdx.x;
    float v = (i < C3 * CC) ? w1[i] : wf[i - C3 * CC];
    ushort h = f2b(v);
    Whi[i] = h;
    Wlo[i] = f2b(v - b2f(h));
}

// ---------------------------------------------------------------------------
// prep_xt: transpose band of x -> Xt[p][k] bf16 hi (RNE).  Batched by y.
// ---------------------------------------------------------------------------
__global__ __launch_bounds__(256) void prep_xt(const float* __restrict__ x,
                                               ushort* __restrict__ Xhi,
                                               int n0, int h0, int BH,
                                               size_t XTIMG) {
    const int n = n0 + blockIdx.y;
    Xhi += (size_t)blockIdx.y * XTIMG;

    const int p0 = blockIdx.x * 64;
    const int gh = h0 - 2 + (p0 >> 8);
    const int wcol = p0 & 255;
    const int t = threadIdx.x;

    if (gh < 0 || gh >= HH) {
        uint* H = (uint*)(Xhi + (size_t)p0 * CC);
        for (int e = t; e < 64 * CC / 2; e += 256) H[e] = 0u;
        return;
    }

    __shared__ float xs[CC][65];
    const float* xb = x + ((size_t)n * CC) * (HH * WW) + (size_t)gh * WW + wcol;
    for (int e = t; e < CC * 16; e += 256) {
        int ic = e >> 4, j = e & 15;
        float4 v = *(const float4*)(xb + (size_t)ic * (HH * WW) + j * 4);
        xs[ic][j * 4 + 0] = v.x;
        xs[ic][j * 4 + 1] = v.y;
        xs[ic][j * 4 + 2] = v.z;
        xs[ic][j * 4 + 3] = v.w;
    }
    __syncthreads();

    const int r = t >> 2;
    const int k0 = (t & 3) * 48;
    uint* H = (uint*)(Xhi + ((size_t)p0 + r) * CC + k0);
    #pragma unroll
    for (int j = 0; j < 48; j += 2) {
        H[j >> 1] = (uint)f2b(xs[k0 + j][r]) | ((uint)f2b(xs[k0 + j + 1][r]) << 16);
    }
}

// ---------------------------------------------------------------------------
// dev_gemm: one 256-thread virtual gemm block (half h of a 512 phys block).
// 2-product split (W hi/lo x B hi).  i = local gemm block; xcd = i&7 (the
// chunked interleave guarantees i == pbid mod 8).  idx2 = 2*(i>>3)+h walks
// per-XCD work; dummy blocks (idx2 >= vpx) run all barriers, skip stores.
// B element (p,k) at Bhi + (k>>5)*SS + p*RS + (k&31).
// ---------------------------------------------------------------------------
template<bool OUTBF16>
__device__ __forceinline__ void dev_gemm(int i, int h, int vt, char* smem,
                                         const ushort* __restrict__ Whi,
                                         const ushort* __restrict__ Wlo,
                                         const ushort* __restrict__ Bhi,
                                         void* __restrict__ Cout, int ldc,
                                         int RS, int SS, int NM, int vpx) {
    ushort (*lA)[64][64] = (ushort (*)[64][64])smem;        // [2][64][64] 16 KB
    ushort (*lB)[64]     = (ushort (*)[64])(smem + 16384);  // [128][64]   16 KB

    const int xcd = i & 7;
    int idx2 = ((i >> 3) << 1) | h;
    const bool live = idx2 < vpx;
    if (!live) idx2 = 0;
    const int ptpx = vpx / NM;
    const int mtile = (idx2 % NM) * 64;
    const int ptile = (xcd * ptpx + idx2 / NM) * 128;

    const int wv = vt >> 6, ln = vt & 63;
    const int wm = wv >> 1, wn = wv & 1;

    f32x4 zero = {0.f, 0.f, 0.f, 0.f};
    f32x4 acc[2][4];
    #pragma unroll
    for (int fm = 0; fm < 2; ++fm)
        #pragma unroll
        for (int fn = 0; fn < 4; ++fn) acc[fm][fn] = zero;

    const int r8 = ln >> 3, s = ln & 7;

    for (int kk = 0; kk < 3; ++kk) {
        const int k0 = kk * 64;
        #pragma unroll
        for (int ci = 0; ci < 8; ++ci) {
            const int c = wv * 8 + ci;
            const ushort* g;
            void* l;
            if (c < 16) {               // A (weights), 2 planes x 8 chunks
                const int pl = c >> 3, ch = c & 7;
                const int r = ch * 8 + r8;
                g = (pl ? Wlo : Whi) + (size_t)(mtile + r) * CC + k0 + ((s ^ (r & 7)) << 3);
                l = (void*)&lA[pl][ch * 8][0];
            } else {                    // B, 16 chunks
                const int ch = c - 16;
                const int r = ch * 8 + r8;
                const int kq = k0 + ((s ^ (r & 7)) << 3);
                g = Bhi + (size_t)(kq >> 5) * (size_t)SS
                        + (size_t)(ptile + r) * (size_t)RS + (kq & 31);
                l = (void*)&lB[ch * 8][0];
            }
            gl_lds16(g, l);
        }
        __syncthreads();

        #pragma unroll
        for (int ks = 0; ks < 2; ++ks) {
            bf16x8 ah[2], al[2], bh[4];
            #pragma unroll
            for (int fm = 0; fm < 2; ++fm) {
                const int r = wm * 32 + fm * 16 + (ln & 15);
                const int col = (((ks * 4 + (ln >> 4)) ^ (r & 7)) << 3);
                ah[fm] = *(const bf16x8*)&lA[0][r][col];
                al[fm] = *(const bf16x8*)&lA[1][r][col];
            }
            #pragma unroll
            for (int fn = 0; fn < 4; ++fn) {
                const int r = wn * 64 + fn * 16 + (ln & 15);
                const int col = (((ks * 4 + (ln >> 4)) ^ (r & 7)) << 3);
                bh[fn] = *(const bf16x8*)&lB[r][col];
            }
            #pragma unroll
            for (int fm = 0; fm < 2; ++fm)
                #pragma unroll
                for (int fn = 0; fn < 4; ++fn) {
                    acc[fm][fn] = __builtin_amdgcn_mfma_f32_16x16x32_bf16(ah[fm], bh[fn], acc[fm][fn], 0, 0, 0);
                    acc[fm][fn] = __builtin_amdgcn_mfma_f32_16x16x32_bf16(al[fm], bh[fn], acc[fm][fn], 0, 0, 0);
                }
        }
        __syncthreads();
    }

    if (live) {
        #pragma unroll
        for (int fm = 0; fm < 2; ++fm)
            #pragma unroll
            for (int fn = 0; fn < 4; ++fn)
                #pragma unroll
                for (int r = 0; r < 4; ++r) {
                    const int m = mtile + wm * 32 + fm * 16 + (ln >> 4) * 4 + r;
                    const int p = ptile + wn * 64 + fn * 16 + (ln & 15);
                    if (OUTBF16)
                        ((ushort*)Cout)[(size_t)m * ldc + p] = f2b(acc[fm][fn][r]);
                    else
                        ((float*)Cout)[(size_t)m * ldc + p] = acc[fm][fn][r];
                }
    }
}

// ---------------------------------------------------------------------------
// dev_k2: register-rolling fused dw3x3 -> dw3x3, one (channel, strip) per
// wave (gid).  No LDS, no barriers.  q,k truncation-packed; v RNE permuted.
// ---------------------------------------------------------------------------
struct RowH { float4 v; float l, r; };

__device__ __forceinline__ RowH k2_expand(ushort4 p, int ln) {
    RowH q;
    q.v = make_float4(bu(p.x), bu(p.y), bu(p.z), bu(p.w));
    q.l = __shfl_up(q.v.w, 1);
    q.r = __shfl_down(q.v.x, 1);
    if (ln == 0) q.l = 0.f;
    if (ln == 63) q.r = 0.f;
    return q;
}

__device__ __forceinline__ float4 k2_conv(const RowH& a, const RowH& b, const RowH& c,
                                          const float* w) {
    float4 o;
    o.x = fmaf(a.l,   w[0], fmaf(a.v.x, w[1], fmaf(a.v.y, w[2],
          fmaf(b.l,   w[3], fmaf(b.v.x, w[4], fmaf(b.v.y, w[5],
          fmaf(c.l,   w[6], fmaf(c.v.x, w[7], c.v.y * w[8]))))))));
    o.y = fmaf(a.v.x, w[0], fmaf(a.v.y, w[1], fmaf(a.v.z, w[2],
          fmaf(b.v.x, w[3], fmaf(b.v.y, w[4], fmaf(b.v.z, w[5],
          fmaf(c.v.x, w[6], fmaf(c.v.y, w[7], c.v.z * w[8]))))))));
    o.z = fmaf(a.v.y, w[0], fmaf(a.v.z, w[1], fmaf(a.v.w, w[2],
          fmaf(b.v.y, w[3], fmaf(b.v.z, w[4], fmaf(b.v.w, w[5],
          fmaf(c.v.y, w[6], fmaf(c.v.z, w[7], c.v.w * w[8]))))))));
    o.w = fmaf(a.v.z, w[0], fmaf(a.v.w, w[1], fmaf(a.r,   w[2],
          fmaf(b.v.z, w[3], fmaf(b.v.w, w[4], fmaf(b.r,   w[5],
          fmaf(c.v.z, w[6], fmaf(c.v.w, w[7], c.r * w[8]))))))));
    return o;
}

__device__ __forceinline__ RowH k2_mid(const RowH& a, const RowH& b, const RowH& c,
                                       const float* w, bool zero, int ln) {
    RowH m;
    if (zero) {
        m.v = make_float4(0.f, 0.f, 0.f, 0.f);
        m.l = 0.f; m.r = 0.f;
        return m;
    }
    m.v = k2_conv(a, b, c, w);
    m.l = __shfl_up(m.v.w, 1);
    m.r = __shfl_down(m.v.x, 1);
    if (ln == 0) m.l = 0.f;
    if (ln == 63) m.r = 0.f;
    return m;
}

__device__ __forceinline__ void dev_k2(int gid, int ln,
                                       const ushort* __restrict__ A,
                                       const float* __restrict__ w2,
                                       const float* __restrict__ w3,
                                       ushort* __restrict__ Bqk,
                                       ushort* __restrict__ Bvh,
                                       int h0, int BH, int strips) {
    const int SR = BH / strips;
    const int c = gid / strips;
    const int s = gid - c * strips;
    const int r0 = s * SR;

    float w2c[9], w3c[9];
    #pragma unroll
    for (int i = 0; i < 9; ++i) { w2c[i] = w2[c * 9 + i]; w3c[i] = w3[c * 9 + i]; }

    const ushort* Ac = A + (size_t)c * (BH + 4) * WW + 4 * ln;

    RowH i0 = k2_expand(*(const ushort4*)(Ac + (size_t)(r0 + 0) * WW), ln);
    RowH i1 = k2_expand(*(const ushort4*)(Ac + (size_t)(r0 + 1) * WW), ln);
    RowH i2 = k2_expand(*(const ushort4*)(Ac + (size_t)(r0 + 2) * WW), ln);
    ushort4 pf = *(const ushort4*)(Ac + (size_t)(r0 + 3) * WW);
    RowH m0 = k2_mid(i0, i1, i2, w2c, (h0 + r0 - 1) < 0, ln);
    i0 = i1; i1 = i2; i2 = k2_expand(pf, ln);
    pf = *(const ushort4*)(Ac + (size_t)(r0 + 4) * WW);
    RowH m1 = k2_mid(i0, i1, i2, w2c, false, ln);

    if (c < 2 * CC) {
        ushort* Bc = Bqk + (size_t)c * BH * WW + 4 * ln;
        #pragma unroll 4
        for (int r = r0; r < r0 + SR; ++r) {
            i0 = i1; i1 = i2; i2 = k2_expand(pf, ln);
            const int rn = (r + 5 < BH + 4) ? r + 5 : BH + 3;
            pf = *(const ushort4*)(Ac + (size_t)rn * WW);
            RowH m2 = k2_mid(i0, i1, i2, w2c, (h0 + r + 1) >= HH, ln);
            float4 o = k2_conv(m0, m1, m2, w3c);
            uint2 ob;
            ob.x = pk2(o.x, o.y);
            ob.y = pk2(o.z, o.w);
            *(uint2*)(Bc + (size_t)r * WW) = ob;
            m0 = m1; m1 = m2;
        }
    } else {
        ushort* Bc = Bvh + (size_t)(c - 2 * CC) * BH * WW;
        const int kp4 = 32 * (ln >> 3) + 8 * (ln & 3) + 4 * ((ln >> 2) & 1);
        #pragma unroll 4
        for (int r = r0; r < r0 + SR; ++r) {
            i0 = i1; i1 = i2; i2 = k2_expand(pf, ln);
            const int rn = (r + 5 < BH + 4) ? r + 5 : BH + 3;
            pf = *(const ushort4*)(Ac + (size_t)rn * WW);
            RowH m2 = k2_mid(i0, i1, i2, w2c, (h0 + r + 1) >= HH, ln);
            float4 o = k2_conv(m0, m1, m2, w3c);
            uint2 ob;
            ob.x = (uint)f2b(o.x) | ((uint)f2b(o.y) << 16);
            ob.y = (uint)f2b(o.z) | ((uint)f2b(o.w) << 16);
            *(uint2*)(Bc + (size_t)r * WW + kp4) = ob;
            m0 = m1; m1 = m2;
        }
    }
}

// ---------------------------------------------------------------------------
// dev_k3: row-wise attention, full 512-thread block, 32 KB smem (passed in).
// ---------------------------------------------------------------------------
__device__ __forceinline__ void dev_k3(int idx, int t, char* smem,
                                       const ushort* __restrict__ Bqk,
                                       const ushort* __restrict__ Bvh,
                                       const float* __restrict__ factor,
                                       ushort* __restrict__ Ohi, int BH) {
    const int r = idx / NHD;
    const int head = idx % NHD;
    const size_t plane = (size_t)BH * WW;

    ushort* Ksp = (ushort*)smem;            // [256][32] 16 KB
    ushort* Vt  = (ushort*)(smem + 16384);  // [32][256] 16 KB swizzled
    uint*   Oar = (uint*)smem;              // epilogue alias

    const int wv = t >> 6, ln = t & 63;
    const int hig = ln >> 4, lo16 = ln & 15;
    const float fsc = factor[0];
    const float L2E = 1.4426950408889634f;
    const float mb2 = fabsf(fsc) * L2E;

    #pragma unroll
    for (int it = 0; it < 2; ++it) {
        const int G = (wv * 2 + it) * 64 + ln;
        const int d = G >> 5, g = G & 31;
        const ushort* src = Bvh + ((size_t)(head * DH + d) * BH + r) * WW
                                + ((g ^ (d & 7)) << 3);
        gl_lds16(src, (void*)(Vt + (size_t)(wv * 2 + it) * 512));
    }

    float qv[2][8];
    #pragma unroll
    for (int c = 0; c < 2; ++c) {
        const int qrow = wv * 32 + c * 16 + lo16;
        const ushort* qb = Bqk + ((size_t)(head * DH + hig * 8)) * plane + (size_t)r * WW + qrow;
        #pragma unroll
        for (int j = 0; j < 8; ++j) qv[c][j] = bu(qb[(size_t)j * plane]);
    }

    if (t < 256) {
        const int row = t;
        const ushort* base = Bqk + ((size_t)(CC + head * DH)) * plane + (size_t)r * WW + row;
        float v[32];
        #pragma unroll
        for (int d = 0; d < 32; ++d) v[d] = bu(base[(size_t)d * plane]);
        float ss = 0.f;
        #pragma unroll
        for (int d = 0; d < 32; ++d) ss = fmaf(v[d], v[d], ss);
        const float inv = 1.f / fmaxf(sqrtf(ss), 1e-12f);
        const int sw = (row >> 1) & 3;
        #pragma unroll
        for (int gq = 0; gq < 4; ++gq) {
            uint hu[4];
            #pragma unroll
            for (int j = 0; j < 4; ++j) {
                float v0 = v[gq * 8 + 2 * j] * inv, v1 = v[gq * 8 + 2 * j + 1] * inv;
                hu[j] = (uint)f2b(v0) | ((uint)f2b(v1) << 16);
            }
            const int off = row * 32 + ((gq ^ sw) << 3);
            *(uint4*)&Ksp[off] = make_uint4(hu[0], hu[1], hu[2], hu[3]);
        }
    }
    __syncthreads();

    union { bf16x8 v; uint u[4]; } qh_[2];
    #pragma unroll
    for (int c = 0; c < 2; ++c) {
        float ssq = 0.f;
        #pragma unroll
        for (int j = 0; j < 8; ++j) ssq = fmaf(qv[c][j], qv[c][j], ssq);
        ssq += __shfl_xor(ssq, 16);
        ssq += __shfl_xor(ssq, 32);
        const float qinv = fsc * L2E / fmaxf(sqrtf(ssq), 1e-12f);
        #pragma unroll
        for (int j = 0; j < 8; j += 2) {
            float v0 = qv[c][j] * qinv, v1 = qv[c][j + 1] * qinv;
            qh_[c].u[j >> 1] = (uint)f2b(v0) | ((uint)f2b(v1) << 16);
        }
    }

    f32x4 osave[2][2];
    float invl[2];

    #pragma unroll
    for (int c = 0; c < 2; ++c) {
        f32x4 s[16];
        const f32x4 cinit = {-mb2, -mb2, -mb2, -mb2};
        __builtin_amdgcn_s_setprio(1);
        #pragma unroll
        for (int f = 0; f < 16; ++f) {
            const int krow = f * 16 + lo16;
            const int koff = krow * 32 + ((hig ^ ((krow >> 1) & 3)) << 3);
            const bf16x8 kh = *(const bf16x8*)&Ksp[koff];
            s[f] = __builtin_amdgcn_mfma_f32_16x16x32_bf16(kh, qh_[c].v, cinit, 0, 0, 0);
        }
        __builtin_amdgcn_s_setprio(0);

        float lsum = 0.f;
        #pragma unroll
        for (int f = 0; f < 16; ++f) {
            #pragma unroll
            for (int rr = 0; rr < 4; ++rr) {
                float p = exp2_fast(s[f][rr]);
                s[f][rr] = p;
                lsum += p;
            }
        }
        lsum += __shfl_xor(lsum, 16);
        lsum += __shfl_xor(lsum, 32);
        invl[c] = 1.f / lsum;

        uint pu[32];
        #pragma unroll
        for (int f = 0; f < 16; ++f) {
            pu[2 * f]     = pk2(s[f][0], s[f][1]);
            pu[2 * f + 1] = pk2(s[f][2], s[f][3]);
        }

        f32x4 o0a = {0,0,0,0}, o0b = {0,0,0,0}, o1a = {0,0,0,0}, o1b = {0,0,0,0};
        __builtin_amdgcn_s_setprio(1);
        #pragma unroll
        for (int st = 0; st < 8; ++st) {
            union { bf16x8 v; uint u[4]; } pb;
            pb.u[0] = pu[4 * st];     pb.u[1] = pu[4 * st + 1];
            pb.u[2] = pu[4 * st + 2]; pb.u[3] = pu[4 * st + 3];
            {
                const int drow = lo16;
                const int voff = drow * 256 + (((4 * st + hig) ^ (drow & 7)) << 3);
                const bf16x8 vh = *(const bf16x8*)&Vt[voff];
                f32x4& o = (st & 1) ? o0b : o0a;
                o = __builtin_amdgcn_mfma_f32_16x16x32_bf16(vh, pb.v, o, 0, 0, 0);
            }
            {
                const int drow = 16 + lo16;
                const int voff = drow * 256 + (((4 * st + hig) ^ (drow & 7)) << 3);
                const bf16x8 vh = *(const bf16x8*)&Vt[voff];
                f32x4& o = (st & 1) ? o1b : o1a;
                o = __builtin_amdgcn_mfma_f32_16x16x32_bf16(vh, pb.v, o, 0, 0, 0);
            }
        }
        __builtin_amdgcn_s_setprio(0);
        #pragma unroll
        for (int rr = 0; rr < 4; ++rr) { o0a[rr] += o0b[rr]; o1a[rr] += o1b[rr]; }
        osave[c][0] = o0a;
        osave[c][1] = o1a;
    }

    __syncthreads();

    #pragma unroll
    for (int c = 0; c < 2; ++c) {
        const int qrow = wv * 32 + c * 16 + lo16;
        #pragma unroll
        for (int fm = 0; fm < 2; ++fm) {
            const f32x4 o = osave[c][fm];
            const float s0 = o[0] * invl[c], s1 = o[1] * invl[c];
            const float s2 = o[2] * invl[c], s3 = o[3] * invl[c];
            const int dp = 8 * fm + 2 * hig;
            Oar[qrow * 20 + dp]     = (uint)f2b(s0) | ((uint)f2b(s1) << 16);
            Oar[qrow * 20 + dp + 1] = (uint)f2b(s2) | ((uint)f2b(s3) << 16);
        }
    }
    __syncthreads();

    if (t < 256) {
        const size_t obase = ((size_t)head * (size_t)BH * WW + (size_t)r * WW + t) * DH;
        uint4* dh_ = (uint4*)(Ohi + obase);
        const uint* srcH = &Oar[t * 20];
        #pragma unroll
        for (int i = 0; i < 4; ++i) dh_[i] = *(const uint4*)&srcH[i * 4];
    }
}

// ---------------------------------------------------------------------------
// Fused kernels.  Each physical 512-thread block runs exactly ONE type
// (block-uniform branch -> barrier-safe).
// ---------------------------------------------------------------------------
__global__ __launch_bounds__(512) void fuse_k2_gemm(
    const ushort* kA, const float* w2, const float* w3, ushort* kBqk, ushort* kBvh,
    int h0, int BH, int strips,
    const ushort* Whi, const ushort* Wlo, const ushort* gB, void* gC,
    int ldc, int RS, int SS, int NM, int vpx,
    int NA, int NBc, int TTH, int tailA) {
    __shared__ __align__(16) char smem[65536];
    int isA, idx;
    pick(blockIdx.x, 8, 16, NA, NBc, TTH, tailA, isA, idx);
    const int t = threadIdx.x;
    if (isA) {
        dev_k2(idx * 8 + (t >> 6), t & 63, kA, w2, w3, kBqk, kBvh, h0, BH, strips);
    } else {
        const int h = t >> 8;
        dev_gemm<true>(idx, h, t & 255, smem + h * 32768, Whi, Wlo, gB, gC, ldc, RS, SS, NM, vpx);
    }
}

__global__ __launch_bounds__(512) void fuse_k3_k2(
    const ushort* aBqk, const ushort* aBvh, const float* factor, ushort* aO, int BH,
    const ushort* kA, const float* w2, const float* w3, ushort* kBqk, ushort* kBvh,
    int h0, int strips,
    int NA, int NBc, int TTH, int tailA) {
    __shared__ __align__(16) char smem[32768];
    int isA, idx;
    pick(blockIdx.x, 8, 8, NA, NBc, TTH, tailA, isA, idx);
    const int t = threadIdx.x;
    if (isA) {
        dev_k3(idx, t, smem, aBqk, aBvh, factor, aO, BH);
    } else {
        dev_k2(idx * 8 + (t >> 6), t & 63, kA, w2, w3, kBqk, kBvh, h0, BH, strips);
    }
}

__global__ __launch_bounds__(512) void fuse_gemm_k3(
    const ushort* Whi, const ushort* Wlo, const ushort* gB, void* gC,
    int ldc, int RS, int SS, int NM, int vpx,
    const ushort* bBqk, const ushort* bBvh, const float* factor, ushort* bO, int BH,
    int NA, int NBc, int TTH, int tailA) {
    __shared__ __align__(16) char smem[65536];
    int isA, idx;
    pick(blockIdx.x, 8, 16, NA, NBc, TTH, tailA, isA, idx);
    const int t = threadIdx.x;
    if (isA) {
        const int h = t >> 8;
        dev_gemm<false>(idx, h, t & 255, smem + h * 32768, Whi, Wlo, gB, gC, ldc, RS, SS, NM, vpx);
    } else {
        dev_k3(idx, t, smem, bBqk, bBvh, factor, bO, BH);
    }
}

extern "C" void kernel_launch(void* const* d_in, const int* in_sizes, int n_in,
                              void* d_out, int out_size, void* d_ws, size_t ws_size,
                              hipStream_t stream) {
    const float* x      = (const float*)d_in[0];
    const float* w1     = (const float*)d_in[1];
    const float* w2     = (const float*)d_in[2];
    const float* w3     = (const float*)d_in[3];
    const float* factor = (const float*)d_in[4];
    const float* wf     = (const float*)d_in[5];
    float* out = (float*)d_out;

    const size_t SW = (size_t)(C3 + CC) * CC * 2 * sizeof(ushort);

    int BH = 256;
    while (BH > 32) {
        size_t SA_ = (size_t)C3 * (BH + 4) * WW * 2;
        size_t SB_ = (size_t)BH * WW * C3 * 2;
        if (2 * (SA_ + SB_) + SW <= ws_size) break;
        BH >>= 1;
    }
    const size_t SA = (size_t)C3 * (BH + 4) * WW * 2;   // per image bytes
    const size_t SB = (size_t)BH * WW * C3 * 2;

    ushort* A    = (ushort*)d_ws;                              // 2 x A/O region
    ushort* Breg = (ushort*)((char*)d_ws + 2 * SA);            // 2 x (Bqk+Bvh / Xt)
    ushort* Wsp  = (ushort*)((char*)d_ws + 2 * (SA + SB));
    ushort* Whi  = Wsp;
    ushort* Wlo  = Wsp + (size_t)(C3 + CC) * CC;
    ushort* Wfhi = Whi + (size_t)C3 * CC;
    ushort* Wflo = Wlo + (size_t)C3 * CC;

    const size_t AIMG = SA / 2;      // ushort stride per image
    const size_t BIMG = SB / 2;
    const size_t QKOFF = (size_t)2 * CC * BH * WW;

    ushort* A0 = A;              ushort* A1 = A + AIMG;
    ushort* X0 = Breg;           ushort* X1 = Breg + BIMG;
    ushort* Bqk0 = Breg;         ushort* Bqk1 = Breg + BIMG;
    ushort* Bvh0 = Bqk0 + QKOFF; ushort* Bvh1 = Bqk1 + QKOFF;
    float*  out0 = out;          float*  out1 = out + (size_t)CC * HH * WW;

    const int strips = BH / 16;
    const int physK2 = C3 * strips / 8;
    const int physK3 = NHD * BH;
    const int nvb1 = ((BH + 4) * WW / 128) * (C3 / 64);
    const int vpx1 = nvb1 / 8;
    const int physG1 = 8 * ((vpx1 + 1) / 2);
    const int ldc1 = (BH + 4) * WW;
    const int nvb2 = (BH * WW / 128) * (CC / 64);
    const int vpx2 = nvb2 / 8;
    const int physG2 = 8 * ((vpx2 + 1) / 2);
    const int SS2 = BH * WW * DH;

    prep_w<<<dim3((C3 + CC) * CC / 256), dim3(256), 0, stream>>>(w1, wf, Whi, Wlo);

    for (int h0 = 0; h0 < HH; h0 += BH) {
        // stage 0: transpose both images' bands
        prep_xt<<<dim3((BH + 4) * (WW / 64), 2), dim3(256), 0, stream>>>(
            x, Breg, 0, h0, BH, BIMG);
        // stage 1: gemm1(img0) alone  (fuse kernel, NA=0)
        fuse_k2_gemm<<<dim3(physG1), dim3(512), 0, stream>>>(
            A1, w2, w3, Bqk1, Bvh1, h0, BH, strips,
            Whi, Wlo, X0, (void*)A0, ldc1, CC, DH, C3 / 64, vpx1,
            0, physG1, 0, 0);
        // stage 2: k2(img0) || gemm1(img1)
        fuse_k2_gemm<<<dim3(physK2 + physG1), dim3(512), 0, stream>>>(
            A0, w2, w3, Bqk0, Bvh0, h0, BH, strips,
            Whi, Wlo, X1, (void*)A1, ldc1, CC, DH, C3 / 64, vpx1,
            physK2, physG1, (physK2 / 8) * 24, 0);
        // stage 3: k3(img0) || k2(img1)
        fuse_k3_k2<<<dim3(physK3 + physK2), dim3(512), 0, stream>>>(
            Bqk0, Bvh0, factor, A0, BH,
            A1, w2, w3, Bqk1, Bvh1, h0, strips,
            physK3, physK2, (physK2 / 8) * 16, 1);
        // stage 4: gemm2(img0) || k3(img1)
        fuse_gemm_k3<<<dim3(physG2 + physK3), dim3(512), 0, stream>>>(
            Wfhi, Wflo, A0, (void*)(out0 + (size_t)h0 * WW), HH * WW,
            DH, SS2, CC / 64, vpx2,
            Bqk1, Bvh1, factor, A1, BH,
            physG2, physK3, physG2 + physK3, 0);
        // stage 5: gemm2(img1) alone
        fuse_gemm_k3<<<dim3(physG2), dim3(512), 0, stream>>>(
            Wfhi, Wflo, A1, (void*)(out1 + (size_t)h0 * WW), HH * WW,
            DH, SS2, CC / 64, vpx2,
            Bqk1, Bvh1, factor, A1, BH,
            physG2, 0, 0, 1);
    }
}

// Round 20
// 291.528 us; speedup vs baseline: 1.1033x; 1.1033x over previous
//
#include <hip/hip_runtime.h>
#include <hip/hip_bf16.h>
#include <math.h>

#define NB 2
#define CC 192
#define HH 256
#define WW 256
#define NHD 6
#define DH 32
#define C3 576   // 3*CC

typedef __attribute__((ext_vector_type(8))) short bf16x8;
typedef __attribute__((ext_vector_type(4))) float f32x4;

__device__ __forceinline__ ushort f2b(float v) {
    __hip_bfloat16 b = __float2bfloat16(v);
    return *reinterpret_cast<ushort*>(&b);
}
__device__ __forceinline__ float b2f(ushort u) {
    __hip_bfloat16 b;
    *reinterpret_cast<ushort*>(&b) = u;
    return __bfloat162float(b);
}
__device__ __forceinline__ float bu(ushort u) {       // bf16 -> f32 (bit shift)
    uint x = (uint)u << 16;
    return __uint_as_float(x);
}
__device__ __forceinline__ float exp2_fast(float x) {
#if __has_builtin(__builtin_amdgcn_exp2f)
    return __builtin_amdgcn_exp2f(x);
#else
    return exp2f(x);
#endif
}
// truncation-pack two fp32 into one uint of 2 bf16 (ONLY safe where a
// downstream normalization cancels the systematic shrink: P, q, k)
__device__ __forceinline__ uint pk2(float x, float y) {
    return (__float_as_uint(y) & 0xFFFF0000u) | (__float_as_uint(x) >> 16);
}

__device__ __forceinline__ void gl_lds16(const void* g, void* l) {
    __builtin_amdgcn_global_load_lds((const __attribute__((address_space(1))) void*)g,
                                     (__attribute__((address_space(3))) void*)l, 16, 0, 0);
}

// ---------------------------------------------------------------------------
// prep_w: split w1[576x192] and wf[192x192] fp32 -> bf16 hi/lo planes.
// ---------------------------------------------------------------------------
__global__ __launch_bounds__(256) void prep_w(const float* __restrict__ w1,
                                              const float* __restrict__ wf,
                                              ushort* __restrict__ Whi,
                                              ushort* __restrict__ Wlo) {
    int i = blockIdx.x * 256 + threadIdx.x;       // < 147456
    float v = (i < C3 * CC) ? w1[i] : wf[i - C3 * CC];
    ushort h = f2b(v);
    Whi[i] = h;
    Wlo[i] = f2b(v - b2f(h));
}

// ---------------------------------------------------------------------------
// prep_xt: transpose band of x -> Xt[p][k] bf16 (HI ONLY, RNE — feeds the
// un-normalized v path), p = a*256+w.  Batched via blockIdx.y.
// ---------------------------------------------------------------------------
__global__ __launch_bounds__(256) void prep_xt(const float* __restrict__ x,
                                               ushort* __restrict__ Xhi,
                                               int n0, int h0, int BH,
                                               size_t XTIMG) {
    const int n = n0 + blockIdx.y;
    Xhi += (size_t)blockIdx.y * XTIMG;

    const int p0 = blockIdx.x * 64;
    const int gh = h0 - 2 + (p0 >> 8);
    const int wcol = p0 & 255;
    const int t = threadIdx.x;

    if (gh < 0 || gh >= HH) {
        uint* H = (uint*)(Xhi + (size_t)p0 * CC);
        for (int e = t; e < 64 * CC / 2; e += 256) H[e] = 0u;
        return;
    }

    __shared__ float xs[CC][65];
    const float* xb = x + ((size_t)n * CC) * (HH * WW) + (size_t)gh * WW + wcol;
    for (int e = t; e < CC * 16; e += 256) {
        int ic = e >> 4, j = e & 15;
        float4 v = *(const float4*)(xb + (size_t)ic * (HH * WW) + j * 4);
        xs[ic][j * 4 + 0] = v.x;
        xs[ic][j * 4 + 1] = v.y;
        xs[ic][j * 4 + 2] = v.z;
        xs[ic][j * 4 + 3] = v.w;
    }
    __syncthreads();

    const int r = t >> 2;            // local position 0..63
    const int k0 = (t & 3) * 48;     // k-chunk
    uint* H = (uint*)(Xhi + ((size_t)p0 + r) * CC + k0);
    #pragma unroll
    for (int j = 0; j < 48; j += 2) {
        H[j >> 1] = (uint)f2b(xs[k0 + j][r]) | ((uint)f2b(xs[k0 + j + 1][r]) << 16);
    }
}

// ---------------------------------------------------------------------------
// gemm_split: C[M][N] = W[M][192] * B[192][N].
// BSPLIT=false: 2 products (W split, B hi-only).  OUTBF16 selects C dtype
// (RNE — A feeds the v path).  Batched via blockIdx.y.  XCD-chunked swizzle.
// B element (p,k) at Bpl + (k>>5)*SS + p*RS + (k&31)  [ushort units].
// ---------------------------------------------------------------------------
template<bool BSPLIT, bool OUTBF16>
__global__ __launch_bounds__(256) void gemm_split(const ushort* __restrict__ Whi,
                                                  const ushort* __restrict__ Wlo,
                                                  const ushort* __restrict__ Bhi,
                                                  const ushort* __restrict__ Blo,
                                                  void* __restrict__ Cout, int ldc,
                                                  int RS, int SS, int NM,
                                                  size_t BIMG, size_t CIMGB) {
    __shared__ ushort lA[2][64][64];                     // 16 KB
    __shared__ ushort lB[BSPLIT ? 2 : 1][128][64];       // 32 / 16 KB

    Bhi += (size_t)blockIdx.y * BIMG;
    if (BSPLIT) Blo += (size_t)blockIdx.y * BIMG;
    Cout = (void*)((char*)Cout + (size_t)blockIdx.y * CIMGB);

    const int bid = blockIdx.x;
    const int xcd = bid & 7;
    const int idx = bid >> 3;
    const int ptpx = (int)(gridDim.x >> 3) / NM;
    const int mtile = (idx % NM) * 64;
    const int ptile = (xcd * ptpx + idx / NM) * 128;

    const int t = threadIdx.x, wv = t >> 6, ln = t & 63;
    const int wm = wv >> 1, wn = wv & 1;

    f32x4 zero = {0.f, 0.f, 0.f, 0.f};
    f32x4 acc[2][4];
    #pragma unroll
    for (int fm = 0; fm < 2; ++fm)
        #pragma unroll
        for (int fn = 0; fn < 4; ++fn) acc[fm][fn] = zero;

    const int r8 = ln >> 3, s = ln & 7;
    const int CPW = BSPLIT ? 12 : 8;

    for (int kk = 0; kk < 3; ++kk) {
        const int k0 = kk * 64;
        #pragma unroll
        for (int ci = 0; ci < CPW; ++ci) {
            const int c = wv * CPW + ci;
            const ushort* g;
            void* l;
            if (c < 16) {               // A (weights), 2 planes x 8 chunks
                const int pl = c >> 3, ch = c & 7;
                const int r = ch * 8 + r8;
                g = (pl ? Wlo : Whi) + (size_t)(mtile + r) * CC + k0 + ((s ^ (r & 7)) << 3);
                l = (void*)&lA[pl][ch * 8][0];
            } else {                    // B (activations)
                const int c2 = c - 16;
                const int pl = BSPLIT ? (c2 >> 4) : 0;
                const int ch = BSPLIT ? (c2 & 15) : c2;
                const int r = ch * 8 + r8;
                const int kq = k0 + ((s ^ (r & 7)) << 3);
                g = ((BSPLIT && pl) ? Blo : Bhi) + (size_t)(kq >> 5) * (size_t)SS
                                      + (size_t)(ptile + r) * (size_t)RS + (kq & 31);
                l = (void*)&lB[pl][ch * 8][0];
            }
            gl_lds16(g, l);
        }
        __syncthreads();

        #pragma unroll
        for (int ks = 0; ks < 2; ++ks) {
            bf16x8 ah[2], al[2], bh[4], bl[4];
            #pragma unroll
            for (int fm = 0; fm < 2; ++fm) {
                const int r = wm * 32 + fm * 16 + (ln & 15);
                const int col = (((ks * 4 + (ln >> 4)) ^ (r & 7)) << 3);
                ah[fm] = *(const bf16x8*)&lA[0][r][col];
                al[fm] = *(const bf16x8*)&lA[1][r][col];
            }
            #pragma unroll
            for (int fn = 0; fn < 4; ++fn) {
                const int r = wn * 64 + fn * 16 + (ln & 15);
                const int col = (((ks * 4 + (ln >> 4)) ^ (r & 7)) << 3);
                bh[fn] = *(const bf16x8*)&lB[0][r][col];
                if (BSPLIT) bl[fn] = *(const bf16x8*)&lB[1][r][col];
            }
            #pragma unroll
            for (int fm = 0; fm < 2; ++fm)
                #pragma unroll
                for (int fn = 0; fn < 4; ++fn) {
                    acc[fm][fn] = __builtin_amdgcn_mfma_f32_16x16x32_bf16(ah[fm], bh[fn], acc[fm][fn], 0, 0, 0);
                    if (BSPLIT)
                        acc[fm][fn] = __builtin_amdgcn_mfma_f32_16x16x32_bf16(ah[fm], bl[fn], acc[fm][fn], 0, 0, 0);
                    acc[fm][fn] = __builtin_amdgcn_mfma_f32_16x16x32_bf16(al[fm], bh[fn], acc[fm][fn], 0, 0, 0);
                }
        }
        __syncthreads();
    }

    #pragma unroll
    for (int fm = 0; fm < 2; ++fm)
        #pragma unroll
        for (int fn = 0; fn < 4; ++fn)
            #pragma unroll
            for (int r = 0; r < 4; ++r) {
                const int m = mtile + wm * 32 + fm * 16 + (ln >> 4) * 4 + r;
                const int p = ptile + wn * 64 + fn * 16 + (ln & 15);
                if (OUTBF16)
                    ((ushort*)Cout)[(size_t)m * ldc + p] = f2b(acc[fm][fn][r]);
                else
                    ((float*)Cout)[(size_t)m * ldc + p] = acc[fm][fn][r];
            }
}

// ---------------------------------------------------------------------------
// K2: register-rolling fused dw3x3(w2) -> dw3x3(w3).  No LDS.
// ONE ushort4 load per row + shfl halos (direct neighbor loads regressed:
// +2 VMEM/row; fused-pipeline block-fusion also regressed: LDS/VGPR coupling
// killed occupancy).  q,k truncation-packed; v RNE.  Prefetch distance 1.
// ---------------------------------------------------------------------------
struct RowH { float4 v; float l, r; };

__device__ __forceinline__ RowH k2_expand(ushort4 p, int ln) {
    RowH q;
    q.v = make_float4(bu(p.x), bu(p.y), bu(p.z), bu(p.w));
    q.l = __shfl_up(q.v.w, 1);
    q.r = __shfl_down(q.v.x, 1);
    if (ln == 0) q.l = 0.f;
    if (ln == 63) q.r = 0.f;
    return q;
}

__device__ __forceinline__ float4 k2_conv(const RowH& a, const RowH& b, const RowH& c,
                                          const float* w) {
    float4 o;
    o.x = fmaf(a.l,   w[0], fmaf(a.v.x, w[1], fmaf(a.v.y, w[2],
          fmaf(b.l,   w[3], fmaf(b.v.x, w[4], fmaf(b.v.y, w[5],
          fmaf(c.l,   w[6], fmaf(c.v.x, w[7], c.v.y * w[8]))))))));
    o.y = fmaf(a.v.x, w[0], fmaf(a.v.y, w[1], fmaf(a.v.z, w[2],
          fmaf(b.v.x, w[3], fmaf(b.v.y, w[4], fmaf(b.v.z, w[5],
          fmaf(c.v.x, w[6], fmaf(c.v.y, w[7], c.v.z * w[8]))))))));
    o.z = fmaf(a.v.y, w[0], fmaf(a.v.z, w[1], fmaf(a.v.w, w[2],
          fmaf(b.v.y, w[3], fmaf(b.v.z, w[4], fmaf(b.v.w, w[5],
          fmaf(c.v.y, w[6], fmaf(c.v.z, w[7], c.v.w * w[8]))))))));
    o.w = fmaf(a.v.z, w[0], fmaf(a.v.w, w[1], fmaf(a.r,   w[2],
          fmaf(b.v.z, w[3], fmaf(b.v.w, w[4], fmaf(b.r,   w[5],
          fmaf(c.v.z, w[6], fmaf(c.v.w, w[7], c.r * w[8]))))))));
    return o;
}

__device__ __forceinline__ RowH k2_mid(const RowH& a, const RowH& b, const RowH& c,
                                       const float* w, bool zero, int ln) {
    RowH m;
    if (zero) {
        m.v = make_float4(0.f, 0.f, 0.f, 0.f);
        m.l = 0.f; m.r = 0.f;
        return m;
    }
    m.v = k2_conv(a, b, c, w);
    m.l = __shfl_up(m.v.w, 1);
    m.r = __shfl_down(m.v.x, 1);
    if (ln == 0) m.l = 0.f;
    if (ln == 63) m.r = 0.f;
    return m;
}

__global__ __launch_bounds__(256) void k2_dwdw(const ushort* __restrict__ A,
                                               const float* __restrict__ w2,
                                               const float* __restrict__ w3,
                                               ushort* __restrict__ Bqk,
                                               ushort* __restrict__ Bvh,
                                               int h0, int BH, int strips,
                                               size_t AIMG, size_t BIMG) {
    A   += (size_t)blockIdx.y * AIMG;
    Bqk += (size_t)blockIdx.y * BIMG;
    Bvh += (size_t)blockIdx.y * BIMG;

    const int SR = BH / strips;                  // 16
    const int wv = threadIdx.x >> 6, ln = threadIdx.x & 63;
    const int gid = blockIdx.x * 4 + wv;
    const int c = gid / strips;
    const int s = gid - c * strips;
    const int r0 = s * SR;

    float w2c[9], w3c[9];
    #pragma unroll
    for (int i = 0; i < 9; ++i) { w2c[i] = w2[c * 9 + i]; w3c[i] = w3[c * 9 + i]; }

    const ushort* Ac = A + (size_t)c * (BH + 4) * WW + 4 * ln;

    RowH i0 = k2_expand(*(const ushort4*)(Ac + (size_t)(r0 + 0) * WW), ln);
    RowH i1 = k2_expand(*(const ushort4*)(Ac + (size_t)(r0 + 1) * WW), ln);
    RowH i2 = k2_expand(*(const ushort4*)(Ac + (size_t)(r0 + 2) * WW), ln);
    ushort4 pf = *(const ushort4*)(Ac + (size_t)(r0 + 3) * WW);
    RowH m0 = k2_mid(i0, i1, i2, w2c, (h0 + r0 - 1) < 0, ln);
    i0 = i1; i1 = i2; i2 = k2_expand(pf, ln);
    pf = *(const ushort4*)(Ac + (size_t)(r0 + 4) * WW);
    RowH m1 = k2_mid(i0, i1, i2, w2c, false, ln);

    if (c < 2 * CC) {      // q,k channels -> bf16, TRUNCATION pack (norm cancels)
        ushort* Bc = Bqk + (size_t)c * BH * WW + 4 * ln;
        #pragma unroll 4
        for (int r = r0; r < r0 + SR; ++r) {
            i0 = i1; i1 = i2; i2 = k2_expand(pf, ln);
            const int rn = (r + 5 < BH + 4) ? r + 5 : BH + 3;
            pf = *(const ushort4*)(Ac + (size_t)rn * WW);
            RowH m2 = k2_mid(i0, i1, i2, w2c, (h0 + r + 1) >= HH, ln);
            float4 o = k2_conv(m0, m1, m2, w3c);
            uint2 ob;
            ob.x = pk2(o.x, o.y);
            ob.y = pk2(o.z, o.w);
            *(uint2*)(Bc + (size_t)r * WW) = ob;
            m0 = m1; m1 = m2;
        }
    } else {               // v channels -> bf16 RNE, kp-permuted columns
        ushort* Bc = Bvh + (size_t)(c - 2 * CC) * BH * WW;
        const int kp4 = 32 * (ln >> 3) + 8 * (ln & 3) + 4 * ((ln >> 2) & 1);
        #pragma unroll 4
        for (int r = r0; r < r0 + SR; ++r) {
            i0 = i1; i1 = i2; i2 = k2_expand(pf, ln);
            const int rn = (r + 5 < BH + 4) ? r + 5 : BH + 3;
            pf = *(const ushort4*)(Ac + (size_t)rn * WW);
            RowH m2 = k2_mid(i0, i1, i2, w2c, (h0 + r + 1) >= HH, ln);
            float4 o = k2_conv(m0, m1, m2, w3c);
            uint2 ob;
            ob.x = (uint)f2b(o.x) | ((uint)f2b(o.y) << 16);
            ob.y = (uint)f2b(o.z) | ((uint)f2b(o.w) << 16);
            *(uint2*)(Bc + (size_t)r * WW + kp4) = ob;
            m0 = m1; m1 = m2;
        }
    }
}

// ---------------------------------------------------------------------------
// K3 (MFMA): row-wise attention, 32 KB LDS, (512,4).  All-bf16 hi-only.
// V staged by global_load_lds from kp-permuted Bvh.  Batched via blockIdx.y.
// ---------------------------------------------------------------------------
__global__ __launch_bounds__(512, 4) void k3_attn_mfma(const ushort* __restrict__ Bqk,
                                                       const ushort* __restrict__ Bvh,
                                                       const float* __restrict__ factor,
                                                       ushort* __restrict__ Ohi, int BH,
                                                       size_t BIMG, size_t OIMG) {
    Bqk += (size_t)blockIdx.y * BIMG;
    Bvh += (size_t)blockIdx.y * BIMG;
    Ohi += (size_t)blockIdx.y * OIMG;

    const int r = blockIdx.x / NHD;
    const int head = blockIdx.x % NHD;
    const int t = threadIdx.x;
    const size_t plane = (size_t)BH * WW;

    __shared__ __align__(16) char arena[32768];
    ushort* Ksp = (ushort*)arena;            // [256 key][32 d]  16 KB
    ushort* Vt  = (ushort*)(arena + 16384);  // [32 d][256 key'] 16 KB (swizzled)
    uint*   Oar = (uint*)arena;              // [256][20] epilogue alias (20 KB)

    const int wv = t >> 6, ln = t & 63;
    const int hig = ln >> 4, lo16 = ln & 15;
    const float fsc = factor[0];
    const float L2E = 1.4426950408889634f;
    const float mb2 = fabsf(fsc) * L2E;

    // ---- V staging: 2 global_load_lds per thread (async, issued first) ----
    #pragma unroll
    for (int it = 0; it < 2; ++it) {
        const int G = (wv * 2 + it) * 64 + ln;          // granule 0..1023
        const int d = G >> 5, g = G & 31;
        const ushort* src = Bvh + ((size_t)(head * DH + d) * BH + r) * WW
                                + ((g ^ (d & 7)) << 3);
        gl_lds16(src, (void*)(Vt + (size_t)(wv * 2 + it) * 512));
    }

    // ---- hoist q global loads (bf16) ----
    float qv[2][8];
    #pragma unroll
    for (int c = 0; c < 2; ++c) {
        const int qrow = wv * 32 + c * 16 + lo16;
        const ushort* qb = Bqk + ((size_t)(head * DH + hig * 8)) * plane + (size_t)r * WW + qrow;
        #pragma unroll
        for (int j = 0; j < 8; ++j) qv[c][j] = bu(qb[(size_t)j * plane]);
    }

    if (t < 256) {
        // ---- stage K row t from bf16: normalize, hi-only, wide stores ----
        const int row = t;
        const ushort* base = Bqk + ((size_t)(CC + head * DH)) * plane + (size_t)r * WW + row;
        float v[32];
        #pragma unroll
        for (int d = 0; d < 32; ++d) v[d] = bu(base[(size_t)d * plane]);
        float ss = 0.f;
        #pragma unroll
        for (int d = 0; d < 32; ++d) ss = fmaf(v[d], v[d], ss);
        const float inv = 1.f / fmaxf(sqrtf(ss), 1e-12f);
        const int sw = (row >> 1) & 3;
        #pragma unroll
        for (int gq = 0; gq < 4; ++gq) {
            uint hu[4];
            #pragma unroll
            for (int j = 0; j < 4; ++j) {
                float v0 = v[gq * 8 + 2 * j] * inv, v1 = v[gq * 8 + 2 * j + 1] * inv;
                hu[j] = (uint)f2b(v0) | ((uint)f2b(v1) << 16);
            }
            const int off = row * 32 + ((gq ^ sw) << 3);
            *(uint4*)&Ksp[off] = make_uint4(hu[0], hu[1], hu[2], hu[3]);
        }
    }
    __syncthreads();

    // ---- q: coop-norm (x factor x log2e), hi-only pack ----
    union { bf16x8 v; uint u[4]; } qh_[2];
    #pragma unroll
    for (int c = 0; c < 2; ++c) {
        float ssq = 0.f;
        #pragma unroll
        for (int j = 0; j < 8; ++j) ssq = fmaf(qv[c][j], qv[c][j], ssq);
        ssq += __shfl_xor(ssq, 16);
        ssq += __shfl_xor(ssq, 32);
        const float qinv = fsc * L2E / fmaxf(sqrtf(ssq), 1e-12f);
        #pragma unroll
        for (int j = 0; j < 8; j += 2) {
            float v0 = qv[c][j] * qinv, v1 = qv[c][j + 1] * qinv;
            qh_[c].u[j >> 1] = (uint)f2b(v0) | ((uint)f2b(v1) << 16);
        }
    }

    f32x4 osave[2][2];
    float invl[2];

    #pragma unroll
    for (int c = 0; c < 2; ++c) {
        f32x4 s[16];
        const f32x4 cinit = {-mb2, -mb2, -mb2, -mb2};
        __builtin_amdgcn_s_setprio(1);
        #pragma unroll
        for (int f = 0; f < 16; ++f) {
            const int krow = f * 16 + lo16;
            const int koff = krow * 32 + ((hig ^ ((krow >> 1) & 3)) << 3);
            const bf16x8 kh = *(const bf16x8*)&Ksp[koff];
            s[f] = __builtin_amdgcn_mfma_f32_16x16x32_bf16(kh, qh_[c].v, cinit, 0, 0, 0);
        }
        __builtin_amdgcn_s_setprio(0);

        float lsum = 0.f;
        #pragma unroll
        for (int f = 0; f < 16; ++f) {
            #pragma unroll
            for (int rr = 0; rr < 4; ++rr) {
                float p = exp2_fast(s[f][rr]);
                s[f][rr] = p;
                lsum += p;
            }
        }
        lsum += __shfl_xor(lsum, 16);
        lsum += __shfl_xor(lsum, 32);
        invl[c] = 1.f / lsum;

        uint pu[32];
        #pragma unroll
        for (int f = 0; f < 16; ++f) {
            pu[2 * f]     = pk2(s[f][0], s[f][1]);
            pu[2 * f + 1] = pk2(s[f][2], s[f][3]);
        }

        // ---- PV: 1 MFMA per (st, drow-half) — V hi-only ----
        f32x4 o0a = {0,0,0,0}, o0b = {0,0,0,0}, o1a = {0,0,0,0}, o1b = {0,0,0,0};
        __builtin_amdgcn_s_setprio(1);
        #pragma unroll
        for (int st = 0; st < 8; ++st) {
            union { bf16x8 v; uint u[4]; } pb;
            pb.u[0] = pu[4 * st];     pb.u[1] = pu[4 * st + 1];
            pb.u[2] = pu[4 * st + 2]; pb.u[3] = pu[4 * st + 3];
            {
                const int drow = lo16;
                const int voff = drow * 256 + (((4 * st + hig) ^ (drow & 7)) << 3);
                const bf16x8 vh = *(const bf16x8*)&Vt[voff];
                f32x4& o = (st & 1) ? o0b : o0a;
                o = __builtin_amdgcn_mfma_f32_16x16x32_bf16(vh, pb.v, o, 0, 0, 0);
            }
            {
                const int drow = 16 + lo16;
                const int voff = drow * 256 + (((4 * st + hig) ^ (drow & 7)) << 3);
                const bf16x8 vh = *(const bf16x8*)&Vt[voff];
                f32x4& o = (st & 1) ? o1b : o1a;
                o = __builtin_amdgcn_mfma_f32_16x16x32_bf16(vh, pb.v, o, 0, 0, 0);
            }
        }
        __builtin_amdgcn_s_setprio(0);
        #pragma unroll
        for (int rr = 0; rr < 4; ++rr) { o0a[rr] += o0b[rr]; o1a[rr] += o1b[rr]; }
        osave[c][0] = o0a;
        osave[c][1] = o1a;
    }

    __syncthreads();   // Ksp/Vt dead before Oar overwrite

    // ---- scale + bf16 (RNE) + transpose through LDS ----
    #pragma unroll
    for (int c = 0; c < 2; ++c) {
        const int qrow = wv * 32 + c * 16 + lo16;
        #pragma unroll
        for (int fm = 0; fm < 2; ++fm) {
            const f32x4 o = osave[c][fm];
            const float s0 = o[0] * invl[c], s1 = o[1] * invl[c];
            const float s2 = o[2] * invl[c], s3 = o[3] * invl[c];
            const int dp = 8 * fm + 2 * hig;
            Oar[qrow * 20 + dp]     = (uint)f2b(s0) | ((uint)f2b(s1) << 16);
            Oar[qrow * 20 + dp + 1] = (uint)f2b(s2) | ((uint)f2b(s3) << 16);
        }
    }
    __syncthreads();

    // ---- per-block contiguous writes: O[head][r*256+t][32] ----
    if (t < 256) {
        const size_t obase = ((size_t)head * (size_t)BH * WW + (size_t)r * WW + t) * DH;
        uint4* dh_ = (uint4*)(Ohi + obase);
        const uint* srcH = &Oar[t * 20];
        #pragma unroll
        for (int i = 0; i < 4; ++i) dh_[i] = *(const uint4*)&srcH[i * 4];
    }
}

extern "C" void kernel_launch(void* const* d_in, const int* in_sizes, int n_in,
                              void* d_out, int out_size, void* d_ws, size_t ws_size,
                              hipStream_t stream) {
    const float* x      = (const float*)d_in[0];
    const float* w1     = (const float*)d_in[1];
    const float* w2     = (const float*)d_in[2];
    const float* w3     = (const float*)d_in[3];
    const float* factor = (const float*)d_in[4];
    const float* wf     = (const float*)d_in[5];
    float* out = (float*)d_out;

    const size_t SW = (size_t)(C3 + CC) * CC * 2 * sizeof(ushort);

    // try fully-batched: both images resident, BH=256
    int BH = 256, NI = 2;
    {
        size_t SA_ = (size_t)C3 * (BH + 4) * WW * 2;
        size_t SB_ = (size_t)BH * WW * C3 * 2;
        if (2 * (SA_ + SB_) + SW > ws_size) NI = 1;
    }
    if (NI == 1) {
        while (BH > 32) {
            size_t SA_ = (size_t)C3 * (BH + 4) * WW * 2;
            size_t SB_ = (size_t)BH * WW * C3 * 2;
            if (SA_ + SB_ + SW <= ws_size) break;
            BH >>= 1;
        }
    }
    const size_t SA = (size_t)C3 * (BH + 4) * WW * 2;     // bytes, per image
    const size_t SB = (size_t)BH * WW * C3 * 2;

    ushort* A    = (ushort*)d_ws;                                  // NI x [576][BH+4][256]
    ushort* Breg = (ushort*)((char*)d_ws + (size_t)NI * SA);       // NI x (Bqk+Bvh)
    ushort* Wsp  = (ushort*)((char*)d_ws + (size_t)NI * (SA + SB));
    ushort* Whi  = Wsp;
    ushort* Wlo  = Wsp + (size_t)(C3 + CC) * CC;

    const size_t AIMG  = SA / 2;                  // ushort stride per image
    const size_t BIMG  = SB / 2;
    const size_t QKOFF = (size_t)2 * CC * BH * WW;   // Bvh offset inside Breg

    prep_w<<<dim3((C3 + CC) * CC / 256), dim3(256), 0, stream>>>(w1, wf, Whi, Wlo);

    const int strips = BH / 16;
    for (int n = 0; n < NB; n += NI) {
        for (int h0 = 0; h0 < HH; h0 += BH) {
            prep_xt<<<dim3((BH + 4) * (WW / 64), NI), dim3(256), 0, stream>>>(
                x, Breg, n, h0, BH, BIMG);
            gemm_split<false, true><<<dim3(((BH + 4) * WW / 128) * (C3 / 64), NI), dim3(256), 0, stream>>>(
                Whi, Wlo, Breg, nullptr, (void*)A, (BH + 4) * WW, CC, DH, C3 / 64,
                BIMG, SA);
            k2_dwdw<<<dim3(C3 * strips / 4, NI), dim3(256), 0, stream>>>(
                A, w2, w3, Breg, Breg + QKOFF, h0, BH, strips, AIMG, BIMG);
            k3_attn_mfma<<<dim3(NHD * BH, NI), dim3(512), 0, stream>>>(
                Breg, Breg + QKOFF, factor, A, BH, BIMG, AIMG);
            gemm_split<false, false><<<dim3((BH * WW / 128) * (CC / 64), NI), dim3(256), 0, stream>>>(
                Whi + (size_t)C3 * CC, Wlo + (size_t)C3 * CC, A, nullptr,
                (void*)(out + ((size_t)n * CC) * HH * WW + (size_t)h0 * WW), HH * WW,
                DH, BH * WW * DH, CC / 64,
                AIMG, (size_t)CC * HH * WW * 4);
        }
    }
}